// Round 12
// baseline (1818.349 us; speedup 1.0000x reference)
//
#include <hip/hip_runtime.h>
#include <cstdint>
#include <cstddef>

#define KNB 20
#define NPTS 8192
#define BATCH 2
#define TOTAL (BATCH * NPTS)

// ---------------------------------------------------------------------------
// K1: pointwise conv 3->64 + relu
// ---------------------------------------------------------------------------
__global__ __launch_bounds__(256) void k_conv(const float* __restrict__ pts,
                                              const float* __restrict__ w,
                                              const float* __restrict__ b,
                                              float* __restrict__ x0) {
  int gid = blockIdx.x * 256 + threadIdx.x;
  if (gid >= TOTAL * 64) return;
  int p = gid >> 6, c = gid & 63;
  float px = pts[p * 3 + 0], py = pts[p * 3 + 1], pz = pts[p * 3 + 2];
  float acc = b[c] + px * w[c] + py * w[64 + c] + pz * w[128 + c];
  x0[gid] = fmaxf(acc, 0.f);
}

// ---------------------------------------------------------------------------
// K2: KNN — TWO waves per query, each scanning one 4096-candidate half
// (halves the serial insert-scan depth vs R11). Per wave: per-lane exact
// top-20 (branchless sorted insert, strict <) + per-tile tau filter
// (bitonic 20th-smallest of lane heads; skipping d2>tau is exact).
// Per-wave top-20 extracted via packed-u64 min (exact (d2,cid) order),
// stored to LDS; wave pairs merged the same way -> exact lax.top_k.
// d2 via __fmul_rn/__fadd_rn: bit-identical to numpy's ((dx²+dy²)+dz²).
// ---------------------------------------------------------------------------
__global__ __launch_bounds__(256) void k_knn(const float* __restrict__ pts,
                                             int* __restrict__ idxbuf) {
  __shared__ float sp[2][3072];                 // 24 KB: [half][tile xyz]
  __shared__ unsigned long long s_top[4][KNB];  // per-wave sorted top-20
  int tid = threadIdx.x;
  int wv = tid >> 6, lane = tid & 63;
  int lq = wv >> 1;        // local query 0/1
  int hf = wv & 1;         // candidate half 0/1
  int q = blockIdx.x * 2 + lq;
  int bq = q >> 13;        // block never straddles batch
  const float* pbase = pts + (size_t)bq * NPTS * 3;
  float qx = pts[q * 3 + 0], qy = pts[q * 3 + 1], qz = pts[q * 3 + 2];

  float dist[KNB];
  int id[KNB];
#pragma unroll
  for (int j = 0; j < KNB; j++) { dist[j] = 3.402823466e38f; id[j] = 0; }
  float tau = 3.402823466e38f;

  for (int t = 0; t < 4; t++) {
    __syncthreads();
    for (int s = tid; s < 3072; s += 256) {
      sp[0][s] = pbase[t * 3072 + s];
      sp[1][s] = pbase[(4 + t) * 3072 + s];
    }
    __syncthreads();

    if (t) {
      // tau = 20th smallest of this wave's 64 lane-heads (ascending bitonic)
      unsigned long long h =
          ((unsigned long long)__float_as_uint(dist[0]) << 32) | (unsigned)id[0];
#pragma unroll
      for (int k = 2; k <= 64; k <<= 1) {
#pragma unroll
        for (int j = k >> 1; j > 0; j >>= 1) {
          unsigned long long o = __shfl_xor(h, j);
          bool up = ((lane & k) == 0);
          bool lower = ((lane & j) == 0);
          bool takeMin = (up == lower);
          bool lt = h < o;
          h = (takeMin == lt) ? h : o;
        }
      }
      tau = __uint_as_float((unsigned)(__shfl(h, 19) >> 32));
    }

    int cid0 = hf * 4096 + t * 1024;
    const float* tp = sp[hf];
#pragma unroll 4
    for (int i = 0; i < 16; i++) {
      int c = lane + (i << 6);
      float dx = qx - tp[c * 3 + 0];
      float dy = qy - tp[c * 3 + 1];
      float dz = qz - tp[c * 3 + 2];
      float d2 = __fadd_rn(__fadd_rn(__fmul_rn(dx, dx), __fmul_rn(dy, dy)),
                           __fmul_rn(dz, dz));
      if (d2 <= tau && d2 < dist[KNB - 1]) {
        int cid = cid0 + c;
#pragma unroll
        for (int j = KNB - 1; j >= 0; j--) {
          bool cj = d2 < dist[j];
          bool cjm1 = (j > 0) && (d2 < dist[j - 1]);
          if (cj) {
            dist[j] = cjm1 ? dist[j - 1] : d2;
            id[j]   = cjm1 ? id[j - 1]   : cid;
          }
        }
      }
    }
  }

  // per-wave extract: 20x min over packed (d2bits, cid) -> s_top[wv]
  for (int step = 0; step < KNB; step++) {
    unsigned long long p =
        ((unsigned long long)__float_as_uint(dist[0]) << 32) | (unsigned)id[0];
    unsigned long long m = p;
#pragma unroll
    for (int off = 32; off >= 1; off >>= 1) {
      unsigned long long o = __shfl_xor(m, off);
      m = (o < m) ? o : m;
    }
    if (lane == 0) s_top[wv][step] = m;
    if (p == m) {
#pragma unroll
      for (int j = 0; j < KNB - 1; j++) { dist[j] = dist[j + 1]; id[j] = id[j + 1]; }
      dist[KNB - 1] = 3.402823466e38f;
    }
  }
  __syncthreads();

  // waves 0/2 merge the two per-half lists for their query (exact order).
  if (hf == 0) {
    unsigned long long v = 0xFFFFFFFFFFFFFFFFULL;   // > any real packed value
    if (lane < KNB) v = s_top[wv][lane];
    else if (lane < 2 * KNB) v = s_top[wv + 1][lane - KNB];
    int bqoff = bq * NPTS;
    for (int step = 0; step < KNB; step++) {
      unsigned long long m = v;
#pragma unroll
      for (int off = 32; off >= 1; off >>= 1) {
        unsigned long long o = __shfl_xor(m, off);
        m = (o < m) ? o : m;
      }
      if (lane == 0) idxbuf[q * KNB + step] = bqoff + (int)(m & 0xffffffffULL);
      if (v == m) v = 0xFFFFFFFFFFFFFFFFULL;
    }
  }
}

// ---------------------------------------------------------------------------
// K3: qkv GEMM (TOTAL,64) @ (64,192) — float4 outputs per thread.
// ---------------------------------------------------------------------------
__global__ __launch_bounds__(256) void k_qkv(const float* __restrict__ x,
                                             const float* __restrict__ w,
                                             float* __restrict__ qkv) {
  int gid = blockIdx.x * 256 + threadIdx.x;
  if (gid >= TOTAL * 48) return;
  int p = gid / 48, c4 = (gid % 48) * 4;
  const float* xr = x + (size_t)p * 64;
  float4 a = make_float4(0.f, 0.f, 0.f, 0.f);
#pragma unroll 8
  for (int k = 0; k < 64; k++) {
    float xv = xr[k];
    float4 wv = *(const float4*)&w[k * 192 + c4];
    a.x += xv * wv.x; a.y += xv * wv.y; a.z += xv * wv.z; a.w += xv * wv.w;
  }
  *(float4*)&qkv[(size_t)p * 192 + c4] = a;
}

// ---------------------------------------------------------------------------
// K3b: kh[g][c] = K_g . aw1_top[:,c]  (K_g = qkv[g][64:128]).
// kh is shared by every query referencing point g -> hoists half of the
// attention hidden-GEMM out of the per-(query,neighbor) loop.
// ---------------------------------------------------------------------------
__global__ __launch_bounds__(256) void k_hh(const float* __restrict__ qkv,
                                            const float* __restrict__ aw1,
                                            float* __restrict__ kh) {
  int gid = blockIdx.x * 256 + threadIdx.x;   // TOTAL*64 threads
  int g = gid >> 6, c4 = (gid & 63) * 4;
  const float* kr = qkv + (size_t)g * 192 + 64;
  float4 a = make_float4(0.f, 0.f, 0.f, 0.f);
#pragma unroll 8
  for (int k = 0; k < 64; k++) {
    float kv = kr[k];
    float4 wv = *(const float4*)&aw1[(size_t)k * 256 + c4];
    a.x += kv * wv.x; a.y += kv * wv.y; a.z += kv * wv.z; a.w += kv * wv.w;
  }
  *(float4*)&kh[(size_t)g * 256 + c4] = a;
}

// ---------------------------------------------------------------------------
// K4: wave-per-query fused attention, LDS-pipe minimized:
//  - hidden = qh - kh[g] + rpe@aw1_bot  (kh precomputed; qh computed in-wave
//    via v_readlane over the register-resident q row): phase-B k-loop 64
//    wide instead of 128 -> 320 broadcast b128 reads (was 640).
//  - A2 (t1@pw2) uses __builtin_amdgcn_readlane to broadcast t1 (register,
//    lane=channel) -> zero LDS traffic for t1 (was 320 reads + 20 writes).
//  - slab = rpe only: 20x64 per wave (20 KB/block).
//  Barriers at phase boundaries (block-uniform; R9/R10 zero-barrier variant
//  correlated with container death — not risked). Register arrays indexed
//  only by fully-unrolled vars (R4 trap). No min-waves launch-bounds (R5).
// ---------------------------------------------------------------------------
__global__ __launch_bounds__(256) void k_attn(
    const float* __restrict__ pos, const float* __restrict__ qkv,
    const int* __restrict__ idxbuf, const float* __restrict__ kh,
    const float* __restrict__ pw1, const float* __restrict__ pb1,
    const float* __restrict__ pw2, const float* __restrict__ pb2,
    const float* __restrict__ aw1, const float* __restrict__ ab1,
    const float* __restrict__ aw2, const float* __restrict__ ab2,
    float* __restrict__ xout) {
  __shared__ float s_rpe[4][KNB][64];   // 20 KB: [wave][n][c]
  __shared__ int   s_nb[4][24];

  int tid = threadIdx.x;
  int wv = tid >> 6, lane = tid & 63;
  int i = blockIdx.x * 4 + wv;

  if (lane < KNB) s_nb[wv][lane] = idxbuf[i * KNB + lane];
  float qv = qkv[(size_t)i * 192 + lane];    // q row, distributed by lane
  float px = pos[i * 3 + 0], py = pos[i * 3 + 1], pz = pos[i * 3 + 2];
  __syncthreads();

  // A1: t1[n] (channel = lane) in REGISTERS
  float t1[KNB];
  {
    float w1x = pw1[lane], w1y = pw1[64 + lane], w1z = pw1[128 + lane];
    float b1h = pb1[lane];
#pragma unroll
    for (int n = 0; n < KNB; n++) {
      int g = s_nb[wv][n];
      float rx = px - pos[g * 3 + 0];
      float ry = py - pos[g * 3 + 1];
      float rz = pz - pos[g * 3 + 2];
      t1[n] = fmaxf(b1h + rx * w1x + ry * w1y + rz * w1z, 0.f);
    }
  }

  // A2: rpe[n][lane] = pb2[lane] + sum_h readlane(t1[n],h) * pw2[h][lane]
#define RL(x, l) __uint_as_float(__builtin_amdgcn_readlane(__float_as_uint(x), (l)))
  {
    float racc[KNB];
    float b2c = pb2[lane];
#pragma unroll
    for (int n = 0; n < KNB; n++) racc[n] = b2c;
#pragma unroll
    for (int h8 = 0; h8 < 64; h8 += 8) {
      float w0 = pw2[(h8 + 0) * 64 + lane];
      float w1 = pw2[(h8 + 1) * 64 + lane];
      float w2 = pw2[(h8 + 2) * 64 + lane];
      float w3 = pw2[(h8 + 3) * 64 + lane];
      float w4 = pw2[(h8 + 4) * 64 + lane];
      float w5 = pw2[(h8 + 5) * 64 + lane];
      float w6 = pw2[(h8 + 6) * 64 + lane];
      float w7 = pw2[(h8 + 7) * 64 + lane];
#pragma unroll
      for (int n = 0; n < KNB; n++) {
        racc[n] += RL(t1[n], h8 + 0) * w0 + RL(t1[n], h8 + 1) * w1 +
                   RL(t1[n], h8 + 2) * w2 + RL(t1[n], h8 + 3) * w3 +
                   RL(t1[n], h8 + 4) * w4 + RL(t1[n], h8 + 5) * w5 +
                   RL(t1[n], h8 + 6) * w6 + RL(t1[n], h8 + 7) * w7;
      }
    }
#pragma unroll
    for (int n = 0; n < KNB; n++) s_rpe[wv][n][lane] = racc[n];
  }
  __syncthreads();

  // B: lane owns hidden cols 4*lane..+3.
  int col0 = lane * 4;
  // qh (once per query): q . aw1_top[:,col]
  float4 qh4 = make_float4(0.f, 0.f, 0.f, 0.f);
#pragma unroll 8
  for (int k = 0; k < 64; k++) {
    float qk = RL(qv, k);
    float4 w = *(const float4*)&aw1[(size_t)k * 256 + col0];
    qh4.x += qk * w.x; qh4.y += qk * w.y; qh4.z += qk * w.z; qh4.w += qk * w.w;
  }
#undef RL
  // acc init = qh - kh[g]
  float acc[KNB][4];
#pragma unroll
  for (int n = 0; n < KNB; n++) {
    int g = s_nb[wv][n];
    float4 kv = *(const float4*)&kh[(size_t)g * 256 + col0];
    acc[n][0] = qh4.x - kv.x; acc[n][1] = qh4.y - kv.y;
    acc[n][2] = qh4.z - kv.z; acc[n][3] = qh4.w - kv.w;
  }
  // + rpe @ aw1_bot (rows 64..127)
#pragma unroll 2
  for (int kc = 0; kc < 64; kc += 4) {
    float4 w0 = *(const float4*)&aw1[(size_t)(64 + kc + 0) * 256 + col0];
    float4 w1 = *(const float4*)&aw1[(size_t)(64 + kc + 1) * 256 + col0];
    float4 w2 = *(const float4*)&aw1[(size_t)(64 + kc + 2) * 256 + col0];
    float4 w3 = *(const float4*)&aw1[(size_t)(64 + kc + 3) * 256 + col0];
#pragma unroll
    for (int n = 0; n < KNB; n++) {
      float4 iv = *(float4*)&s_rpe[wv][n][kc];
      acc[n][0] += iv.x * w0.x + iv.y * w1.x + iv.z * w2.x + iv.w * w3.x;
      acc[n][1] += iv.x * w0.y + iv.y * w1.y + iv.z * w2.y + iv.w * w3.y;
      acc[n][2] += iv.x * w0.z + iv.y * w1.z + iv.z * w2.z + iv.w * w3.z;
      acc[n][3] += iv.x * w0.w + iv.y * w1.w + iv.z * w2.w + iv.w * w3.w;
    }
  }

  // epilogue: sim[n] = relu(hidden+ab1).aw2 + ab2, 64-lane butterfly
  float4 b1v = *(const float4*)&ab1[col0];
  float4 w2v = *(const float4*)&aw2[col0];
  float ab2v = ab2[0];
  float sim[KNB];
#pragma unroll
  for (int n = 0; n < KNB; n++) {
    float s = fmaxf(acc[n][0] + b1v.x, 0.f) * w2v.x +
              fmaxf(acc[n][1] + b1v.y, 0.f) * w2v.y +
              fmaxf(acc[n][2] + b1v.z, 0.f) * w2v.z +
              fmaxf(acc[n][3] + b1v.w, 0.f) * w2v.w;
#pragma unroll
    for (int off = 32; off >= 1; off >>= 1) s += __shfl_xor(s, off);
    sim[n] = s + ab2v;
  }

  // C: softmax over K=20 (redundant per-lane), out = sum attn*(v + rpe)
  float mx = -3.402823466e38f;
#pragma unroll
  for (int n = 0; n < KNB; n++) mx = fmaxf(mx, sim[n]);
  float e[KNB];
  float sum = 0.f;
#pragma unroll
  for (int n = 0; n < KNB; n++) { e[n] = expf(sim[n] - mx); sum += e[n]; }
  float inv = 1.f / sum;
  float o = 0.f;
#pragma unroll
  for (int n = 0; n < KNB; n++) {
    int g = s_nb[wv][n];
    float vnb = qkv[(size_t)g * 192 + 128 + lane] + s_rpe[wv][n][lane];
    o += (e[n] * inv) * vnb;
  }
  xout[(size_t)i * 64 + lane] = o;
}

// ---------------------------------------------------------------------------
// K5: global max-pool + fc1 + fc3 (unchanged)
// ---------------------------------------------------------------------------
__global__ __launch_bounds__(256) void k_final(const float* __restrict__ x,
                                               const float* __restrict__ fc1w,
                                               const float* __restrict__ fc1b,
                                               const float* __restrict__ fc3w,
                                               const float* __restrict__ fc3b,
                                               float* __restrict__ out) {
  __shared__ float red[4][64];
  __shared__ float m[64];
  __shared__ float h1[32];
  int b = blockIdx.x;
  int tid = threadIdx.x;
  int c = tid & 63, pg = tid >> 6;
  float mx = -3.402823466e38f;
  for (int p = pg; p < NPTS; p += 4)
    mx = fmaxf(mx, x[((size_t)b * NPTS + p) * 64 + c]);
  red[pg][c] = mx;
  __syncthreads();
  if (tid < 64)
    m[c] = fmaxf(fmaxf(red[0][c], red[1][c]), fmaxf(red[2][c], red[3][c]));
  __syncthreads();
  if (tid < 32) {
    float a = fc1b[tid];
#pragma unroll 8
    for (int k = 0; k < 64; k++) a += m[k] * fc1w[k * 32 + tid];
    h1[tid] = fmaxf(a, 0.f);
  }
  __syncthreads();
  if (tid < 3) {
    float a = fc3b[tid];
#pragma unroll
    for (int k = 0; k < 32; k++) a += h1[k] * fc3w[k * 3 + tid];
    out[b * 3 + tid] = a;
  }
}

// ---------------------------------------------------------------------------
// Workspace (peak 36.2 MB):
//   idx @ 0      (1.31 MB)  live whole run
//   qkv @ 2 MB   (12.6 MB)  per layer
//   kh  @ 15 MB  (16.8 MB)  per layer (k_hh -> attn)
//   act @ 32 MB  (4.2 MB)   x0/x1/x2 share one slot (each dead before next
//                           writer: conv->qkv1, attn1->qkv2, attn2->final)
// ---------------------------------------------------------------------------
extern "C" void kernel_launch(void* const* d_in, const int* in_sizes, int n_in,
                              void* d_out, int out_size, void* d_ws,
                              size_t ws_size, hipStream_t stream) {
  const float* pts    = (const float*)d_in[0];
  const float* conv_w = (const float*)d_in[1];
  const float* conv_b = (const float*)d_in[2];
  const float* fc1w = (const float*)d_in[21];
  const float* fc1b = (const float*)d_in[22];
  const float* fc3w = (const float*)d_in[23];
  const float* fc3b = (const float*)d_in[24];
  float* outp = (float*)d_out;

  char* ws = (char*)d_ws;
  int*   idx = (int*)  (ws);
  float* qkv = (float*)(ws + (size_t)2 * 1048576);
  float* kh  = (float*)(ws + (size_t)15 * 1048576);
  float* act = (float*)(ws + (size_t)32 * 1048576);

  k_conv<<<(TOTAL * 64 + 255) / 256, 256, 0, stream>>>(pts, conv_w, conv_b, act);
  k_knn<<<TOTAL / 2, 256, 0, stream>>>(pts, idx);

  for (int layer = 0; layer < 2; layer++) {
    int base = 3 + layer * 9;
    const float* qkvw = (const float*)d_in[base + 0];
    const float* aw1  = (const float*)d_in[base + 5];
    k_qkv<<<(TOTAL * 48 + 255) / 256, 256, 0, stream>>>(act, qkvw, qkv);
    k_hh<<<(TOTAL * 64 + 255) / 256, 256, 0, stream>>>(qkv, aw1, kh);
    k_attn<<<TOTAL / 4, 256, 0, stream>>>(
        pts, qkv, idx, kh,
        (const float*)d_in[base + 1], (const float*)d_in[base + 2],
        (const float*)d_in[base + 3], (const float*)d_in[base + 4],
        aw1, (const float*)d_in[base + 6],
        (const float*)d_in[base + 7], (const float*)d_in[base + 8],
        act);
  }
  k_final<<<BATCH, 256, 0, stream>>>(act, fc1w, fc1b, fc3w, fc3b, outp);
}

// Round 13
// 1642.680 us; speedup vs baseline: 1.1069x; 1.1069x over previous
//
#include <hip/hip_runtime.h>
#include <cstdint>
#include <cstddef>

#define KNB 20
#define NPTS 8192
#define BATCH 2
#define TOTAL (BATCH * NPTS)

// ---------------------------------------------------------------------------
// K1: pointwise conv 3->64 + relu
// ---------------------------------------------------------------------------
__global__ __launch_bounds__(256) void k_conv(const float* __restrict__ pts,
                                              const float* __restrict__ w,
                                              const float* __restrict__ b,
                                              float* __restrict__ x0) {
  int gid = blockIdx.x * 256 + threadIdx.x;
  if (gid >= TOTAL * 64) return;
  int p = gid >> 6, c = gid & 63;
  float px = pts[p * 3 + 0], py = pts[p * 3 + 1], pz = pts[p * 3 + 2];
  float acc = b[c] + px * w[c] + py * w[64 + c] + pz * w[128 + c];
  x0[gid] = fmaxf(acc, 0.f);
}

// ---------------------------------------------------------------------------
// K2: KNN — R11 version (PROVEN 512 µs; R12's 2-wave split regressed to 709:
// 64 cand/lane never saturates the lane top-20, insert prob ~1). One wave
// per query; per-tile tau = bitonic 20th-smallest of lane heads (exact
// filter); branchless sorted insert; packed-u64 min-extract merge.
// d2 via __fmul_rn/__fadd_rn: bit-identical to numpy's ((dx²+dy²)+dz²).
// ---------------------------------------------------------------------------
__global__ __launch_bounds__(256) void k_knn(const float* __restrict__ pts,
                                             int* __restrict__ idxbuf) {
  __shared__ float sp[3 * 1024];   // 12 KB candidate tile
  int tid = threadIdx.x;
  int wv = tid >> 6, lane = tid & 63;
  int q = blockIdx.x * 4 + wv;            // 4 queries/block, one per wave
  int bq = q >> 13;                       // block never straddles batch
  const float* pbase = pts + (size_t)bq * NPTS * 3;
  float qx = pts[q * 3 + 0], qy = pts[q * 3 + 1], qz = pts[q * 3 + 2];

  float dist[KNB];
  int id[KNB];
#pragma unroll
  for (int j = 0; j < KNB; j++) { dist[j] = 3.402823466e38f; id[j] = 0; }
  float tau = 3.402823466e38f;

  for (int tile = 0; tile < NPTS; tile += 1024) {
    __syncthreads();
    for (int t = tid; t < 3072; t += 256) sp[t] = pbase[tile * 3 + t];
    __syncthreads();

    if (tile) {
      // tau = 20th smallest of the 64 lane-heads (ascending bitonic).
      unsigned long long h =
          ((unsigned long long)__float_as_uint(dist[0]) << 32) | (unsigned)id[0];
#pragma unroll
      for (int k = 2; k <= 64; k <<= 1) {
#pragma unroll
        for (int j = k >> 1; j > 0; j >>= 1) {
          unsigned long long o = __shfl_xor(h, j);
          bool up = ((lane & k) == 0);
          bool lower = ((lane & j) == 0);
          bool takeMin = (up == lower);
          bool lt = h < o;
          h = (takeMin == lt) ? h : o;
        }
      }
      tau = __uint_as_float((unsigned)(__shfl(h, 19) >> 32));
    }

#pragma unroll 4
    for (int i = 0; i < 16; i++) {
      int c = lane + (i << 6);
      float dx = qx - sp[c * 3 + 0];
      float dy = qy - sp[c * 3 + 1];
      float dz = qz - sp[c * 3 + 2];
      float d2 = __fadd_rn(__fadd_rn(__fmul_rn(dx, dx), __fmul_rn(dy, dy)),
                           __fmul_rn(dz, dz));
      if (d2 <= tau && d2 < dist[KNB - 1]) {
        int cid = tile + c;
        // branchless sorted insert (ascending); strict < keeps lax.top_k
        // stable tie-breaking within a lane.
#pragma unroll
        for (int j = KNB - 1; j >= 0; j--) {
          bool cj = d2 < dist[j];
          bool cjm1 = (j > 0) && (d2 < dist[j - 1]);
          if (cj) {
            dist[j] = cjm1 ? dist[j - 1] : d2;
            id[j]   = cjm1 ? id[j - 1]   : cid;
          }
        }
      }
    }
  }

  // 20-step cross-lane merge: min over packed (d2bits, cid) — exact
  // lax.top_k order (d2 asc, index asc).
  int bqoff = bq * NPTS;
  for (int step = 0; step < KNB; step++) {
    unsigned long long p =
        ((unsigned long long)__float_as_uint(dist[0]) << 32) | (unsigned)id[0];
    unsigned long long m = p;
#pragma unroll
    for (int off = 32; off >= 1; off >>= 1) {
      unsigned long long o = __shfl_xor(m, off);
      m = (o < m) ? o : m;
    }
    if (lane == 0) idxbuf[q * KNB + step] = bqoff + (int)(m & 0xffffffffULL);
    if (p == m) {
#pragma unroll
      for (int j = 0; j < KNB - 1; j++) { dist[j] = dist[j + 1]; id[j] = id[j + 1]; }
      dist[KNB - 1] = 3.402823466e38f;
    }
  }
}

// ---------------------------------------------------------------------------
// K3: qkv GEMM (TOTAL,64) @ (64,192) — float4 outputs per thread.
// ---------------------------------------------------------------------------
__global__ __launch_bounds__(256) void k_qkv(const float* __restrict__ x,
                                             const float* __restrict__ w,
                                             float* __restrict__ qkv) {
  int gid = blockIdx.x * 256 + threadIdx.x;
  if (gid >= TOTAL * 48) return;
  int p = gid / 48, c4 = (gid % 48) * 4;
  const float* xr = x + (size_t)p * 64;
  float4 a = make_float4(0.f, 0.f, 0.f, 0.f);
#pragma unroll 8
  for (int k = 0; k < 64; k++) {
    float xv = xr[k];
    float4 wv = *(const float4*)&w[k * 192 + c4];
    a.x += xv * wv.x; a.y += xv * wv.y; a.z += xv * wv.z; a.w += xv * wv.w;
  }
  *(float4*)&qkv[(size_t)p * 192 + c4] = a;
}

// ---------------------------------------------------------------------------
// K3b: kh[g][c] = K_g . aw1_top[:,c]  (K_g = qkv[g][64:128]); shared by all
// queries referencing g -> hoists half the hidden-GEMM out of attn.
// ---------------------------------------------------------------------------
__global__ __launch_bounds__(256) void k_hh(const float* __restrict__ qkv,
                                            const float* __restrict__ aw1,
                                            float* __restrict__ kh) {
  int gid = blockIdx.x * 256 + threadIdx.x;   // TOTAL*64 threads
  int g = gid >> 6, c4 = (gid & 63) * 4;
  const float* kr = qkv + (size_t)g * 192 + 64;
  float4 a = make_float4(0.f, 0.f, 0.f, 0.f);
#pragma unroll 8
  for (int k = 0; k < 64; k++) {
    float kv = kr[k];
    float4 wv = *(const float4*)&aw1[(size_t)k * 256 + c4];
    a.x += kv * wv.x; a.y += kv * wv.y; a.z += kv * wv.z; a.w += kv * wv.w;
  }
  *(float4*)&kh[(size_t)g * 256 + c4] = a;
}

// ---------------------------------------------------------------------------
// K4: wave-per-query fused attention, VGPR-SLIMMED for 4 waves/SIMD:
//  - phase B split into two passes of 10 neighbors: acc[10][4] = 40 VGPRs
//    (was acc[20][4]=80 -> ~168 count -> 2 waves/SIMD; gather-latency-bound
//    kernel needs occupancy more than fewer aw1 re-loads, which are L1-hot).
//  - hidden = qh - kh[g] + rpe@aw1_bot (kh precomputed; qh via readlane).
//  - A2 via readlane (t1 in regs, dies after A2): LDS/wave stays ~360 ops.
//  Block-uniform barriers only (R9/R10 zero-barrier = container death).
//  Register arrays indexed only by fully-unrolled vars (R4 trap). No
//  min-waves launch-bounds arg (R5 trap).
// ---------------------------------------------------------------------------
__global__ __launch_bounds__(256) void k_attn(
    const float* __restrict__ pos, const float* __restrict__ qkv,
    const int* __restrict__ idxbuf, const float* __restrict__ kh,
    const float* __restrict__ pw1, const float* __restrict__ pb1,
    const float* __restrict__ pw2, const float* __restrict__ pb2,
    const float* __restrict__ aw1, const float* __restrict__ ab1,
    const float* __restrict__ aw2, const float* __restrict__ ab2,
    float* __restrict__ xout) {
  __shared__ float s_rpe[4][KNB][64];   // 20 KB: [wave][n][c]
  __shared__ int   s_nb[4][24];

  int tid = threadIdx.x;
  int wv = tid >> 6, lane = tid & 63;
  int i = blockIdx.x * 4 + wv;

  if (lane < KNB) s_nb[wv][lane] = idxbuf[i * KNB + lane];
  float qv = qkv[(size_t)i * 192 + lane];    // q row, distributed by lane
  float px = pos[i * 3 + 0], py = pos[i * 3 + 1], pz = pos[i * 3 + 2];
  __syncthreads();

#define RL(x, l) __uint_as_float(__builtin_amdgcn_readlane(__float_as_uint(x), (l)))
  // A1+A2: t1 in registers (channel=lane), rpe via readlane broadcast.
  {
    float t1[KNB];
    float w1x = pw1[lane], w1y = pw1[64 + lane], w1z = pw1[128 + lane];
    float b1h = pb1[lane];
#pragma unroll
    for (int n = 0; n < KNB; n++) {
      int g = s_nb[wv][n];
      float rx = px - pos[g * 3 + 0];
      float ry = py - pos[g * 3 + 1];
      float rz = pz - pos[g * 3 + 2];
      t1[n] = fmaxf(b1h + rx * w1x + ry * w1y + rz * w1z, 0.f);
    }
    float racc[KNB];
    float b2c = pb2[lane];
#pragma unroll
    for (int n = 0; n < KNB; n++) racc[n] = b2c;
#pragma unroll
    for (int h8 = 0; h8 < 64; h8 += 8) {
      float w0 = pw2[(h8 + 0) * 64 + lane];
      float w1 = pw2[(h8 + 1) * 64 + lane];
      float w2 = pw2[(h8 + 2) * 64 + lane];
      float w3 = pw2[(h8 + 3) * 64 + lane];
      float w4 = pw2[(h8 + 4) * 64 + lane];
      float w5 = pw2[(h8 + 5) * 64 + lane];
      float w6 = pw2[(h8 + 6) * 64 + lane];
      float w7 = pw2[(h8 + 7) * 64 + lane];
#pragma unroll
      for (int n = 0; n < KNB; n++) {
        racc[n] += RL(t1[n], h8 + 0) * w0 + RL(t1[n], h8 + 1) * w1 +
                   RL(t1[n], h8 + 2) * w2 + RL(t1[n], h8 + 3) * w3 +
                   RL(t1[n], h8 + 4) * w4 + RL(t1[n], h8 + 5) * w5 +
                   RL(t1[n], h8 + 6) * w6 + RL(t1[n], h8 + 7) * w7;
      }
    }
#pragma unroll
    for (int n = 0; n < KNB; n++) s_rpe[wv][n][lane] = racc[n];
  }
  __syncthreads();

  // qh (once per query): q . aw1_top[:,col], lane owns cols 4*lane..+3
  int col0 = lane * 4;
  float4 qh4 = make_float4(0.f, 0.f, 0.f, 0.f);
#pragma unroll 8
  for (int k = 0; k < 64; k++) {
    float qk = RL(qv, k);
    float4 w = *(const float4*)&aw1[(size_t)k * 256 + col0];
    qh4.x += qk * w.x; qh4.y += qk * w.y; qh4.z += qk * w.z; qh4.w += qk * w.w;
  }
#undef RL

  // B: two passes of 10 neighbors (acc[10][4] keeps VGPR < 128)
  float4 b1v = *(const float4*)&ab1[col0];
  float4 w2v = *(const float4*)&aw2[col0];
  float ab2v = ab2[0];
  float sim[KNB];
#pragma unroll
  for (int half = 0; half < 2; half++) {
    int nb0 = half * 10;
    float acc[10][4];
#pragma unroll
    for (int n = 0; n < 10; n++) {
      int g = s_nb[wv][nb0 + n];
      float4 kv = *(const float4*)&kh[(size_t)g * 256 + col0];
      acc[n][0] = qh4.x - kv.x; acc[n][1] = qh4.y - kv.y;
      acc[n][2] = qh4.z - kv.z; acc[n][3] = qh4.w - kv.w;
    }
#pragma unroll 2
    for (int kc = 0; kc < 64; kc += 4) {
      float4 w0 = *(const float4*)&aw1[(size_t)(64 + kc + 0) * 256 + col0];
      float4 w1 = *(const float4*)&aw1[(size_t)(64 + kc + 1) * 256 + col0];
      float4 w2 = *(const float4*)&aw1[(size_t)(64 + kc + 2) * 256 + col0];
      float4 w3 = *(const float4*)&aw1[(size_t)(64 + kc + 3) * 256 + col0];
#pragma unroll
      for (int n = 0; n < 10; n++) {
        float4 iv = *(float4*)&s_rpe[wv][nb0 + n][kc];
        acc[n][0] += iv.x * w0.x + iv.y * w1.x + iv.z * w2.x + iv.w * w3.x;
        acc[n][1] += iv.x * w0.y + iv.y * w1.y + iv.z * w2.y + iv.w * w3.y;
        acc[n][2] += iv.x * w0.z + iv.y * w1.z + iv.z * w2.z + iv.w * w3.z;
        acc[n][3] += iv.x * w0.w + iv.y * w1.w + iv.z * w2.w + iv.w * w3.w;
      }
    }
#pragma unroll
    for (int n = 0; n < 10; n++) {
      float s = fmaxf(acc[n][0] + b1v.x, 0.f) * w2v.x +
                fmaxf(acc[n][1] + b1v.y, 0.f) * w2v.y +
                fmaxf(acc[n][2] + b1v.z, 0.f) * w2v.z +
                fmaxf(acc[n][3] + b1v.w, 0.f) * w2v.w;
#pragma unroll
      for (int off = 32; off >= 1; off >>= 1) s += __shfl_xor(s, off);
      sim[nb0 + n] = s + ab2v;
    }
  }

  // C: softmax over K=20 (redundant per-lane), out = sum attn*(v + rpe)
  float mx = -3.402823466e38f;
#pragma unroll
  for (int n = 0; n < KNB; n++) mx = fmaxf(mx, sim[n]);
  float e[KNB];
  float sum = 0.f;
#pragma unroll
  for (int n = 0; n < KNB; n++) { e[n] = expf(sim[n] - mx); sum += e[n]; }
  float inv = 1.f / sum;
  float o = 0.f;
#pragma unroll
  for (int n = 0; n < KNB; n++) {
    int g = s_nb[wv][n];
    float vnb = qkv[(size_t)g * 192 + 128 + lane] + s_rpe[wv][n][lane];
    o += (e[n] * inv) * vnb;
  }
  xout[(size_t)i * 64 + lane] = o;
}

// ---------------------------------------------------------------------------
// K5: global max-pool + fc1 + fc3 (unchanged)
// ---------------------------------------------------------------------------
__global__ __launch_bounds__(256) void k_final(const float* __restrict__ x,
                                               const float* __restrict__ fc1w,
                                               const float* __restrict__ fc1b,
                                               const float* __restrict__ fc3w,
                                               const float* __restrict__ fc3b,
                                               float* __restrict__ out) {
  __shared__ float red[4][64];
  __shared__ float m[64];
  __shared__ float h1[32];
  int b = blockIdx.x;
  int tid = threadIdx.x;
  int c = tid & 63, pg = tid >> 6;
  float mx = -3.402823466e38f;
  for (int p = pg; p < NPTS; p += 4)
    mx = fmaxf(mx, x[((size_t)b * NPTS + p) * 64 + c]);
  red[pg][c] = mx;
  __syncthreads();
  if (tid < 64)
    m[c] = fmaxf(fmaxf(red[0][c], red[1][c]), fmaxf(red[2][c], red[3][c]));
  __syncthreads();
  if (tid < 32) {
    float a = fc1b[tid];
#pragma unroll 8
    for (int k = 0; k < 64; k++) a += m[k] * fc1w[k * 32 + tid];
    h1[tid] = fmaxf(a, 0.f);
  }
  __syncthreads();
  if (tid < 3) {
    float a = fc3b[tid];
#pragma unroll
    for (int k = 0; k < 32; k++) a += h1[k] * fc3w[k * 3 + tid];
    out[b * 3 + tid] = a;
  }
}

// ---------------------------------------------------------------------------
// Workspace (peak 36.2 MB):
//   idx @ 0      (1.31 MB) | qkv @ 2 MB (12.6 MB) | kh @ 15 MB (16.8 MB)
//   act @ 32 MB  (4.2 MB)  x0/x1/x2 share one slot
// ---------------------------------------------------------------------------
extern "C" void kernel_launch(void* const* d_in, const int* in_sizes, int n_in,
                              void* d_out, int out_size, void* d_ws,
                              size_t ws_size, hipStream_t stream) {
  const float* pts    = (const float*)d_in[0];
  const float* conv_w = (const float*)d_in[1];
  const float* conv_b = (const float*)d_in[2];
  const float* fc1w = (const float*)d_in[21];
  const float* fc1b = (const float*)d_in[22];
  const float* fc3w = (const float*)d_in[23];
  const float* fc3b = (const float*)d_in[24];
  float* outp = (float*)d_out;

  char* ws = (char*)d_ws;
  int*   idx = (int*)  (ws);
  float* qkv = (float*)(ws + (size_t)2 * 1048576);
  float* kh  = (float*)(ws + (size_t)15 * 1048576);
  float* act = (float*)(ws + (size_t)32 * 1048576);

  k_conv<<<(TOTAL * 64 + 255) / 256, 256, 0, stream>>>(pts, conv_w, conv_b, act);
  k_knn<<<TOTAL / 4, 256, 0, stream>>>(pts, idx);

  for (int layer = 0; layer < 2; layer++) {
    int base = 3 + layer * 9;
    const float* qkvw = (const float*)d_in[base + 0];
    const float* aw1  = (const float*)d_in[base + 5];
    k_qkv<<<(TOTAL * 48 + 255) / 256, 256, 0, stream>>>(act, qkvw, qkv);
    k_hh<<<(TOTAL * 64 + 255) / 256, 256, 0, stream>>>(qkv, aw1, kh);
    k_attn<<<TOTAL / 4, 256, 0, stream>>>(
        pts, qkv, idx, kh,
        (const float*)d_in[base + 1], (const float*)d_in[base + 2],
        (const float*)d_in[base + 3], (const float*)d_in[base + 4],
        aw1, (const float*)d_in[base + 6],
        (const float*)d_in[base + 7], (const float*)d_in[base + 8],
        act);
  }
  k_final<<<BATCH, 256, 0, stream>>>(act, fc1w, fc1b, fc3w, fc3b, outp);
}

// Round 14
// 1591.266 us; speedup vs baseline: 1.1427x; 1.0323x over previous
//
#include <hip/hip_runtime.h>
#include <cstdint>
#include <cstddef>

#define KNB 20
#define NPTS 8192
#define BATCH 2
#define TOTAL (BATCH * NPTS)

// ---------------------------------------------------------------------------
// K0: transpose pts to SoA (ptsT[b][dim][p]) so KNN candidate reads are
// 256B/instr coalesced and L1-resident (98 KB per batch).
// ---------------------------------------------------------------------------
__global__ __launch_bounds__(256) void k_pose(const float* __restrict__ pts,
                                              float* __restrict__ ptsT) {
  int gid = blockIdx.x * 256 + threadIdx.x;
  if (gid >= TOTAL * 3) return;
  int pt = gid / 3, d = gid % 3;
  int b = pt >> 13, p = pt & (NPTS - 1);
  ptsT[((size_t)b * 3 + d) * NPTS + p] = pts[gid];
}

// ---------------------------------------------------------------------------
// K1: pointwise conv 3->64 + relu
// ---------------------------------------------------------------------------
__global__ __launch_bounds__(256) void k_conv(const float* __restrict__ pts,
                                              const float* __restrict__ w,
                                              const float* __restrict__ b,
                                              float* __restrict__ x0) {
  int gid = blockIdx.x * 256 + threadIdx.x;
  if (gid >= TOTAL * 64) return;
  int p = gid >> 6, c = gid & 63;
  float px = pts[p * 3 + 0], py = pts[p * 3 + 1], pz = pts[p * 3 + 2];
  float acc = b[c] + px * w[c] + py * w[64 + c] + pz * w[128 + c];
  x0[gid] = fmaxf(acc, 0.f);
}

// ---------------------------------------------------------------------------
// K2: KNN v3 — BARRIER-FREE, NO LDS. One wave per query; candidates read
// straight from the SoA copy (98 KB/batch -> L1/L2-hot; R13's LDS staging
// + 16 block barriers coupled 4 divergent waves -> Occ 31.5%, VALU 49%).
// tau filter per 1024-candidate chunk: bitonic 20th-smallest of the 64
// lane-heads (>= true wave-20th -> skipping d2>tau is EXACT). Lane-local
// branchless sorted insert (strict <); packed-u64 min-extract merge ->
// exact lax.top_k (d2 asc, idx asc) order.
// d2 via __fmul_rn/__fadd_rn: bit-identical to numpy's ((dx²+dy²)+dz²).
// ---------------------------------------------------------------------------
__global__ __launch_bounds__(256) void k_knn(const float* __restrict__ ptsT,
                                             const float* __restrict__ pts,
                                             int* __restrict__ idxbuf) {
  int tid = threadIdx.x;
  int wv = tid >> 6, lane = tid & 63;
  int q = blockIdx.x * 4 + wv;            // 4 independent waves per block
  int bq = q >> 13;
  const float* px = ptsT + (size_t)bq * 3 * NPTS;
  const float* py = px + NPTS;
  const float* pz = py + NPTS;
  float qx = pts[q * 3 + 0], qy = pts[q * 3 + 1], qz = pts[q * 3 + 2];

  float dist[KNB];
  int id[KNB];
#pragma unroll
  for (int j = 0; j < KNB; j++) { dist[j] = 3.402823466e38f; id[j] = 0; }
  float tau = 3.402823466e38f;

  for (int chunk = 0; chunk < 8; chunk++) {
    if (chunk) {
      // tau = 20th smallest of the 64 lane-heads (ascending bitonic).
      unsigned long long h =
          ((unsigned long long)__float_as_uint(dist[0]) << 32) | (unsigned)id[0];
#pragma unroll
      for (int k = 2; k <= 64; k <<= 1) {
#pragma unroll
        for (int j = k >> 1; j > 0; j >>= 1) {
          unsigned long long o = __shfl_xor(h, j);
          bool up = ((lane & k) == 0);
          bool lower = ((lane & j) == 0);
          bool takeMin = (up == lower);
          bool lt = h < o;
          h = (takeMin == lt) ? h : o;
        }
      }
      tau = __uint_as_float((unsigned)(__shfl(h, 19) >> 32));
    }

    int base = chunk * 1024;
#pragma unroll 4
    for (int i = 0; i < 16; i++) {
      int c = base + lane + (i << 6);
      float dx = qx - px[c];
      float dy = qy - py[c];
      float dz = qz - pz[c];
      float d2 = __fadd_rn(__fadd_rn(__fmul_rn(dx, dx), __fmul_rn(dy, dy)),
                           __fmul_rn(dz, dz));
      if (d2 <= tau && d2 < dist[KNB - 1]) {
        int cid = c;
#pragma unroll
        for (int j = KNB - 1; j >= 0; j--) {
          bool cj = d2 < dist[j];
          bool cjm1 = (j > 0) && (d2 < dist[j - 1]);
          if (cj) {
            dist[j] = cjm1 ? dist[j - 1] : d2;
            id[j]   = cjm1 ? id[j - 1]   : cid;
          }
        }
      }
    }
  }

  // 20-step cross-lane merge: min over packed (d2bits, cid).
  int bqoff = bq * NPTS;
  for (int step = 0; step < KNB; step++) {
    unsigned long long p =
        ((unsigned long long)__float_as_uint(dist[0]) << 32) | (unsigned)id[0];
    unsigned long long m = p;
#pragma unroll
    for (int off = 32; off >= 1; off >>= 1) {
      unsigned long long o = __shfl_xor(m, off);
      m = (o < m) ? o : m;
    }
    if (lane == 0) idxbuf[q * KNB + step] = bqoff + (int)(m & 0xffffffffULL);
    if (p == m) {
#pragma unroll
      for (int j = 0; j < KNB - 1; j++) { dist[j] = dist[j + 1]; id[j] = id[j + 1]; }
      dist[KNB - 1] = 3.402823466e38f;
    }
  }
}

// ---------------------------------------------------------------------------
// K3: qkv GEMM (TOTAL,64) @ (64,192) — float4 outputs per thread.
// ---------------------------------------------------------------------------
__global__ __launch_bounds__(256) void k_qkv(const float* __restrict__ x,
                                             const float* __restrict__ w,
                                             float* __restrict__ qkv) {
  int gid = blockIdx.x * 256 + threadIdx.x;
  if (gid >= TOTAL * 48) return;
  int p = gid / 48, c4 = (gid % 48) * 4;
  const float* xr = x + (size_t)p * 64;
  float4 a = make_float4(0.f, 0.f, 0.f, 0.f);
#pragma unroll 8
  for (int k = 0; k < 64; k++) {
    float xv = xr[k];
    float4 wv = *(const float4*)&w[k * 192 + c4];
    a.x += xv * wv.x; a.y += xv * wv.y; a.z += xv * wv.z; a.w += xv * wv.w;
  }
  *(float4*)&qkv[(size_t)p * 192 + c4] = a;
}

// ---------------------------------------------------------------------------
// K3b: kh[g][c] = K_g . aw1_top[:,c]  (K_g = qkv[g][64:128]); shared by all
// queries referencing g -> hoists half the hidden-GEMM out of attn.
// ---------------------------------------------------------------------------
__global__ __launch_bounds__(256) void k_hh(const float* __restrict__ qkv,
                                            const float* __restrict__ aw1,
                                            float* __restrict__ kh) {
  int gid = blockIdx.x * 256 + threadIdx.x;   // TOTAL*64 threads
  int g = gid >> 6, c4 = (gid & 63) * 4;
  const float* kr = qkv + (size_t)g * 192 + 64;
  float4 a = make_float4(0.f, 0.f, 0.f, 0.f);
#pragma unroll 8
  for (int k = 0; k < 64; k++) {
    float kv = kr[k];
    float4 wv = *(const float4*)&aw1[(size_t)k * 256 + c4];
    a.x += kv * wv.x; a.y += kv * wv.y; a.z += kv * wv.z; a.w += kv * wv.w;
  }
  *(float4*)&kh[(size_t)g * 256 + c4] = a;
}

// ---------------------------------------------------------------------------
// K4: wave-per-query fused attention (R13 structure + streaming softmax:
// exp recomputed in the output pass -> e[20] register array dropped; values
// bit-identical). hidden = qh - kh[g] + rpe@aw1_bot; A2 via readlane;
// phase B in two 10-neighbor passes (acc[10][4]).
// Block-uniform barriers only (R9/R10 zero-barrier = container death).
// Register arrays indexed only by fully-unrolled vars (R4 trap). No
// min-waves launch-bounds arg (R5 trap).
// ---------------------------------------------------------------------------
__global__ __launch_bounds__(256) void k_attn(
    const float* __restrict__ pos, const float* __restrict__ qkv,
    const int* __restrict__ idxbuf, const float* __restrict__ kh,
    const float* __restrict__ pw1, const float* __restrict__ pb1,
    const float* __restrict__ pw2, const float* __restrict__ pb2,
    const float* __restrict__ aw1, const float* __restrict__ ab1,
    const float* __restrict__ aw2, const float* __restrict__ ab2,
    float* __restrict__ xout) {
  __shared__ float s_rpe[4][KNB][64];   // 20 KB: [wave][n][c]
  __shared__ int   s_nb[4][24];

  int tid = threadIdx.x;
  int wv = tid >> 6, lane = tid & 63;
  int i = blockIdx.x * 4 + wv;

  if (lane < KNB) s_nb[wv][lane] = idxbuf[i * KNB + lane];
  float qv = qkv[(size_t)i * 192 + lane];    // q row, distributed by lane
  float px = pos[i * 3 + 0], py = pos[i * 3 + 1], pz = pos[i * 3 + 2];
  __syncthreads();

#define RL(x, l) __uint_as_float(__builtin_amdgcn_readlane(__float_as_uint(x), (l)))
  // A1+A2: t1 in registers (channel=lane), rpe via readlane broadcast.
  {
    float t1[KNB];
    float w1x = pw1[lane], w1y = pw1[64 + lane], w1z = pw1[128 + lane];
    float b1h = pb1[lane];
#pragma unroll
    for (int n = 0; n < KNB; n++) {
      int g = s_nb[wv][n];
      float rx = px - pos[g * 3 + 0];
      float ry = py - pos[g * 3 + 1];
      float rz = pz - pos[g * 3 + 2];
      t1[n] = fmaxf(b1h + rx * w1x + ry * w1y + rz * w1z, 0.f);
    }
    float racc[KNB];
    float b2c = pb2[lane];
#pragma unroll
    for (int n = 0; n < KNB; n++) racc[n] = b2c;
#pragma unroll
    for (int h8 = 0; h8 < 64; h8 += 8) {
      float w0 = pw2[(h8 + 0) * 64 + lane];
      float w1 = pw2[(h8 + 1) * 64 + lane];
      float w2 = pw2[(h8 + 2) * 64 + lane];
      float w3 = pw2[(h8 + 3) * 64 + lane];
      float w4 = pw2[(h8 + 4) * 64 + lane];
      float w5 = pw2[(h8 + 5) * 64 + lane];
      float w6 = pw2[(h8 + 6) * 64 + lane];
      float w7 = pw2[(h8 + 7) * 64 + lane];
#pragma unroll
      for (int n = 0; n < KNB; n++) {
        racc[n] += RL(t1[n], h8 + 0) * w0 + RL(t1[n], h8 + 1) * w1 +
                   RL(t1[n], h8 + 2) * w2 + RL(t1[n], h8 + 3) * w3 +
                   RL(t1[n], h8 + 4) * w4 + RL(t1[n], h8 + 5) * w5 +
                   RL(t1[n], h8 + 6) * w6 + RL(t1[n], h8 + 7) * w7;
      }
    }
#pragma unroll
    for (int n = 0; n < KNB; n++) s_rpe[wv][n][lane] = racc[n];
  }
  __syncthreads();

  // qh (once per query): q . aw1_top[:,col], lane owns cols 4*lane..+3
  int col0 = lane * 4;
  float4 qh4 = make_float4(0.f, 0.f, 0.f, 0.f);
#pragma unroll 8
  for (int k = 0; k < 64; k++) {
    float qk = RL(qv, k);
    float4 w = *(const float4*)&aw1[(size_t)k * 256 + col0];
    qh4.x += qk * w.x; qh4.y += qk * w.y; qh4.z += qk * w.z; qh4.w += qk * w.w;
  }
#undef RL

  // B: two passes of 10 neighbors (acc[10][4] keeps VGPR low)
  float4 b1v = *(const float4*)&ab1[col0];
  float4 w2v = *(const float4*)&aw2[col0];
  float ab2v = ab2[0];
  float sim[KNB];
#pragma unroll
  for (int half = 0; half < 2; half++) {
    int nb0 = half * 10;
    float acc[10][4];
#pragma unroll
    for (int n = 0; n < 10; n++) {
      int g = s_nb[wv][nb0 + n];
      float4 kv = *(const float4*)&kh[(size_t)g * 256 + col0];
      acc[n][0] = qh4.x - kv.x; acc[n][1] = qh4.y - kv.y;
      acc[n][2] = qh4.z - kv.z; acc[n][3] = qh4.w - kv.w;
    }
#pragma unroll 2
    for (int kc = 0; kc < 64; kc += 4) {
      float4 w0 = *(const float4*)&aw1[(size_t)(64 + kc + 0) * 256 + col0];
      float4 w1 = *(const float4*)&aw1[(size_t)(64 + kc + 1) * 256 + col0];
      float4 w2 = *(const float4*)&aw1[(size_t)(64 + kc + 2) * 256 + col0];
      float4 w3 = *(const float4*)&aw1[(size_t)(64 + kc + 3) * 256 + col0];
#pragma unroll
      for (int n = 0; n < 10; n++) {
        float4 iv = *(float4*)&s_rpe[wv][nb0 + n][kc];
        acc[n][0] += iv.x * w0.x + iv.y * w1.x + iv.z * w2.x + iv.w * w3.x;
        acc[n][1] += iv.x * w0.y + iv.y * w1.y + iv.z * w2.y + iv.w * w3.y;
        acc[n][2] += iv.x * w0.z + iv.y * w1.z + iv.z * w2.z + iv.w * w3.z;
        acc[n][3] += iv.x * w0.w + iv.y * w1.w + iv.z * w2.w + iv.w * w3.w;
      }
    }
#pragma unroll
    for (int n = 0; n < 10; n++) {
      float s = fmaxf(acc[n][0] + b1v.x, 0.f) * w2v.x +
                fmaxf(acc[n][1] + b1v.y, 0.f) * w2v.y +
                fmaxf(acc[n][2] + b1v.z, 0.f) * w2v.z +
                fmaxf(acc[n][3] + b1v.w, 0.f) * w2v.w;
#pragma unroll
      for (int off = 32; off >= 1; off >>= 1) s += __shfl_xor(s, off);
      sim[nb0 + n] = s + ab2v;
    }
  }

  // C: streaming softmax (exp recomputed -> no e[20] array; bit-identical)
  float mx = -3.402823466e38f;
#pragma unroll
  for (int n = 0; n < KNB; n++) mx = fmaxf(mx, sim[n]);
  float sum = 0.f;
#pragma unroll
  for (int n = 0; n < KNB; n++) sum += expf(sim[n] - mx);
  float inv = 1.f / sum;
  float o = 0.f;
#pragma unroll
  for (int n = 0; n < KNB; n++) {
    int g = s_nb[wv][n];
    float vnb = qkv[(size_t)g * 192 + 128 + lane] + s_rpe[wv][n][lane];
    o += (expf(sim[n] - mx) * inv) * vnb;
  }
  xout[(size_t)i * 64 + lane] = o;
}

// ---------------------------------------------------------------------------
// K5: global max-pool + fc1 + fc3 (unchanged)
// ---------------------------------------------------------------------------
__global__ __launch_bounds__(256) void k_final(const float* __restrict__ x,
                                               const float* __restrict__ fc1w,
                                               const float* __restrict__ fc1b,
                                               const float* __restrict__ fc3w,
                                               const float* __restrict__ fc3b,
                                               float* __restrict__ out) {
  __shared__ float red[4][64];
  __shared__ float m[64];
  __shared__ float h1[32];
  int b = blockIdx.x;
  int tid = threadIdx.x;
  int c = tid & 63, pg = tid >> 6;
  float mx = -3.402823466e38f;
  for (int p = pg; p < NPTS; p += 4)
    mx = fmaxf(mx, x[((size_t)b * NPTS + p) * 64 + c]);
  red[pg][c] = mx;
  __syncthreads();
  if (tid < 64)
    m[c] = fmaxf(fmaxf(red[0][c], red[1][c]), fmaxf(red[2][c], red[3][c]));
  __syncthreads();
  if (tid < 32) {
    float a = fc1b[tid];
#pragma unroll 8
    for (int k = 0; k < 64; k++) a += m[k] * fc1w[k * 32 + tid];
    h1[tid] = fmaxf(a, 0.f);
  }
  __syncthreads();
  if (tid < 3) {
    float a = fc3b[tid];
#pragma unroll
    for (int k = 0; k < 32; k++) a += h1[k] * fc3w[k * 3 + tid];
    out[b * 3 + tid] = a;
  }
}

// ---------------------------------------------------------------------------
// Workspace (peak 36.2 MB):
//   idx  @ 0       (1.31 MB) | ptsT @ 1.5 MB (0.2 MB)
//   qkv  @ 2 MB    (12.6 MB) | kh @ 15 MB (16.8 MB)
//   act  @ 32 MB   (4.2 MB)  x0/x1/x2 share one slot
// ---------------------------------------------------------------------------
extern "C" void kernel_launch(void* const* d_in, const int* in_sizes, int n_in,
                              void* d_out, int out_size, void* d_ws,
                              size_t ws_size, hipStream_t stream) {
  const float* pts    = (const float*)d_in[0];
  const float* conv_w = (const float*)d_in[1];
  const float* conv_b = (const float*)d_in[2];
  const float* fc1w = (const float*)d_in[21];
  const float* fc1b = (const float*)d_in[22];
  const float* fc3w = (const float*)d_in[23];
  const float* fc3b = (const float*)d_in[24];
  float* outp = (float*)d_out;

  char* ws = (char*)d_ws;
  int*   idx  = (int*)  (ws);
  float* ptsT = (float*)(ws + (size_t)1536 * 1024);
  float* qkv  = (float*)(ws + (size_t)2 * 1048576);
  float* kh   = (float*)(ws + (size_t)15 * 1048576);
  float* act  = (float*)(ws + (size_t)32 * 1048576);

  k_pose<<<(TOTAL * 3 + 255) / 256, 256, 0, stream>>>(pts, ptsT);
  k_conv<<<(TOTAL * 64 + 255) / 256, 256, 0, stream>>>(pts, conv_w, conv_b, act);
  k_knn<<<TOTAL / 4, 256, 0, stream>>>(ptsT, pts, idx);

  for (int layer = 0; layer < 2; layer++) {
    int base = 3 + layer * 9;
    const float* qkvw = (const float*)d_in[base + 0];
    const float* aw1  = (const float*)d_in[base + 5];
    k_qkv<<<(TOTAL * 48 + 255) / 256, 256, 0, stream>>>(act, qkvw, qkv);
    k_hh<<<(TOTAL * 64 + 255) / 256, 256, 0, stream>>>(qkv, aw1, kh);
    k_attn<<<TOTAL / 4, 256, 0, stream>>>(
        pts, qkv, idx, kh,
        (const float*)d_in[base + 1], (const float*)d_in[base + 2],
        (const float*)d_in[base + 3], (const float*)d_in[base + 4],
        aw1, (const float*)d_in[base + 6],
        (const float*)d_in[base + 7], (const float*)d_in[base + 8],
        act);
  }
  k_final<<<BATCH, 256, 0, stream>>>(act, fc1w, fc1b, fc3w, fc3b, outp);
}